// Round 1
// 735.891 us; speedup vs baseline: 1.4584x; 1.4584x over previous
//
#include <hip/hip_runtime.h>
#include <stdint.h>

#define N3i 25600
#define N4i 6400
#define N5i 1600
#define NNi 33600
#define ECi 260000
#define EHi 120000

typedef unsigned short u16;
typedef __bf16 bf16x8 __attribute__((ext_vector_type(8)));
typedef float f32x4 __attribute__((ext_vector_type(4)));

__device__ __forceinline__ float b2f(u16 u) {
    union { float f; uint32_t i; } v; v.i = ((uint32_t)u) << 16; return v.f;
}
__device__ __forceinline__ u16 f2b(float f) {
    union { float f; uint32_t i; } v; v.f = f;
    uint32_t x = v.i;
    uint32_t r = (x + 0x7FFFu + ((x >> 16) & 1u)) >> 16;  // RNE
    return (u16)r;
}

// ---------------- dtype detection: flag=1 if inputs are bf16, 0 if fp32 ----------------
__global__ void detect_kernel(const void* __restrict__ c3raw, int* __restrict__ flag) {
    const uint32_t* p = (const uint32_t*)c3raw;
    int t = threadIdx.x;
    int vote = 0;
    for (int i = t; i < 256; i += 64) {
        uint32_t w = p[i];
        uint32_t lo = w & 0xFFFFu;
        uint32_t e = (lo >> 7) & 0xFFu;
        if (lo == 0u || (e >= 100u && e <= 127u)) vote++;
    }
#pragma unroll
    for (int d = 32; d >= 1; d >>= 1) vote += __shfl_down(vote, d, 64);
    if (t == 0) flag[0] = (vote >= 192) ? 1 : 0;
}

// ---------------- utility kernels ----------------
__global__ void zero_i32(int* p, int n) {
    int i = blockIdx.x * 256 + threadIdx.x;
    if (i < n) p[i] = 0;
}

// both histograms in one launch
__global__ void hist2_kernel(const int* __restrict__ dst_c, const int* __restrict__ dst_h,
                             int* __restrict__ cnt_c, int* __restrict__ cnt_h) {
    int i = blockIdx.x * 256 + threadIdx.x;
    if (i < ECi) {
        int d = dst_c[i];
        if ((unsigned)d < (unsigned)NNi) atomicAdd(&cnt_c[d], 1);
    } else {
        int j = i - ECi;
        if (j < EHi) {
            int d = dst_h[j];
            if ((unsigned)d < (unsigned)NNi) atomicAdd(&cnt_h[d], 1);
        }
    }
}

// wave-shuffle scan; blockIdx.x==0 -> contextual, ==1 -> hierarchical (concurrent)
__global__ __launch_bounds__(1024) void scan2_kernel(
    const int* __restrict__ cnt_c, int* __restrict__ rs_c, int* __restrict__ cur_c,
    float* __restrict__ inv_c,
    const int* __restrict__ cnt_h, int* __restrict__ rs_h, int* __restrict__ cur_h,
    float* __restrict__ inv_h, int n) {
    const int* cnt = blockIdx.x ? cnt_h : cnt_c;
    int* rs = blockIdx.x ? rs_h : rs_c;
    int* cur = blockIdx.x ? cur_h : cur_c;
    float* inv = blockIdx.x ? inv_h : inv_c;
    __shared__ int ws[16];
    __shared__ int base;
    int t = threadIdx.x, wid = t >> 6, lane = t & 63;
    if (t == 0) { base = 0; rs[0] = 0; }
    __syncthreads();
    for (int i0 = 0; i0 < n; i0 += 1024) {
        int i = i0 + t;
        int v = (i < n) ? cnt[i] : 0;
        int x = v;
#pragma unroll
        for (int d = 1; d < 64; d <<= 1) {
            int y = __shfl_up(x, d, 64);
            if (lane >= d) x += y;
        }
        if (lane == 63) ws[wid] = x;
        __syncthreads();
        if (wid == 0) {
            int s = (lane < 16) ? ws[lane] : 0;
#pragma unroll
            for (int d = 1; d < 16; d <<= 1) {
                int y = __shfl_up(s, d, 64);
                if (lane >= d) s += y;
            }
            if (lane < 16) ws[lane] = s;
        }
        __syncthreads();
        int b = base;
        int incl = x + (wid ? ws[wid - 1] : 0);
        if (i < n) {
            rs[i + 1] = b + incl;
            cur[i] = b + incl - v;
            int dv = v < 1 ? 1 : v;
            inv[i] = 1.0f / (float)dv;
        }
        int tot = ws[15];
        __syncthreads();
        if (t == 1023) base = b + tot;
        __syncthreads();
    }
}

// both CSR fills in one launch
__global__ void fill2_kernel(const int* __restrict__ src_c, const int* __restrict__ dst_c,
                             int* __restrict__ cur_c, int* __restrict__ csr_c,
                             const int* __restrict__ src_h, const int* __restrict__ dst_h,
                             int* __restrict__ cur_h, int* __restrict__ csr_h) {
    int i = blockIdx.x * 256 + threadIdx.x;
    if (i < ECi) {
        int d = dst_c[i];
        if ((unsigned)d < (unsigned)NNi) {
            int p = atomicAdd(&cur_c[d], 1);
            if ((unsigned)p < (unsigned)ECi) csr_c[p] = src_c[i];
        }
    } else {
        int j = i - ECi;
        if (j < EHi) {
            int d = dst_h[j];
            if ((unsigned)d < (unsigned)NNi) {
                int p = atomicAdd(&cur_h[d], 1);
                if ((unsigned)p < (unsigned)EHi) csr_h[p] = src_h[j];
            }
        }
    }
}

// all 11 small conversions in one launch (grid.y = job id)
struct CvtJobs { const void* src[11]; u16* dst[11]; int n[11]; };

__global__ void cvt_all_kernel(CvtJobs j, const int* __restrict__ flag) {
    int job = blockIdx.y;
    int i = blockIdx.x * 256 + threadIdx.x;
    if (i >= j.n[job]) return;
    const void* s = j.src[job];
    j.dst[job][i] = flag[0] ? ((const u16*)s)[i] : f2b(((const float*)s)[i]);
}

// ---------------- transposes ----------------
// shared tile body: in/out already point at this batch's matrix (element offsets applied)
__device__ __forceinline__ void tin_body(const void* in, size_t ioff, u16* outp, int R, int C,
                                         int isb, int c0, int r0, u16 (*tile)[33]) {
    const u16* inb = (const u16*)in + ioff;
    const float* inf_ = (const float*)in + ioff;
    int tx = threadIdx.x, ty = threadIdx.y;  // block (32,8)
#pragma unroll
    for (int i = 0; i < 4; i++) {
        int r = r0 + ty + i * 8, c = c0 + tx;
        if (r < R && c < C) {
            size_t idx = (size_t)r * C + c;
            tile[ty + i * 8][tx] = isb ? inb[idx] : f2b(inf_[idx]);
        }
    }
    __syncthreads();
#pragma unroll
    for (int i = 0; i < 4; i++) {
        int c = c0 + ty + i * 8, r = r0 + tx;
        if (c < C && r < R) outp[(size_t)c * R + r] = tile[tx][ty + i * 8];
    }
}

// c3/c4/c5 -> Xt3/Xt4/Xt5, one launch; x-range selects level
__global__ void transpose_in3(const void* __restrict__ c3, const void* __restrict__ c4,
                              const void* __restrict__ c5, u16* __restrict__ Xt3,
                              u16* __restrict__ Xt4, u16* __restrict__ Xt5,
                              const int* __restrict__ flag) {
    __shared__ u16 tile[32][33];
    int bx = blockIdx.x;
    const void* in; u16* outb; int R, C, xb;
    if (bx < 200)      { in = c3; outb = Xt3; R = 256; C = 6400; xb = bx; }
    else if (bx < 250) { in = c4; outb = Xt4; R = 512; C = 1600; xb = bx - 200; }
    else               { in = c5; outb = Xt5; R = 512; C = 400;  xb = bx - 250; }
    int r0 = blockIdx.y * 32;
    if (r0 >= R) return;
    size_t boff = (size_t)blockIdx.z * R * C;
    tin_body(in, boff, outb + boff, R, C, flag[0], xb * 32, r0, tile);
}

// Wc (6) + Wh (3) weight transposes, one launch (z = 0..8)
__global__ void transpose_w(const void* __restrict__ Wc, const void* __restrict__ Wh,
                            u16* __restrict__ WtG, const int* __restrict__ flag) {
    __shared__ u16 tile[32][33];
    int z = blockIdx.z;
    const void* in = (z < 6) ? Wc : Wh;
    int zi = (z < 6) ? z : z - 6;
    tin_body(in, (size_t)zi * 65536, WtG + (size_t)z * 65536, 256, 256, flag[0],
             blockIdx.x * 32, blockIdx.y * 32, tile);
}

// node-major -> NCHW output, all 3 levels in one launch; y-range selects level
__global__ void transpose_out3(const u16* __restrict__ OutT, void* __restrict__ outv,
                               const int* __restrict__ flag) {
    __shared__ u16 tile[32][33];
    int by = blockIdx.y;
    const u16* inb; size_t out_off; int R, yb;
    if (by < 200)      { inb = OutT; out_off = 0; R = 6400; yb = by; }
    else if (by < 250) { inb = OutT + (size_t)N3i * 256; out_off = (size_t)4 * 256 * 6400; R = 1600; yb = by - 200; }
    else               { inb = OutT + (size_t)(N3i + N4i) * 256; out_off = (size_t)4 * 256 * 8000; R = 400; yb = by - 250; }
    int r0 = yb * 32;
    if (r0 >= R) return;
    const int C = 256;
    int isb = flag[0];
    int c0 = blockIdx.x * 32;
    size_t boff = (size_t)blockIdx.z * R * C;
    const u16* inp = inb + boff;
    int tx = threadIdx.x, ty = threadIdx.y;
#pragma unroll
    for (int i = 0; i < 4; i++) {
        int r = r0 + ty + i * 8, c = c0 + tx;
        if (r < R && c < C) tile[ty + i * 8][tx] = inp[(size_t)r * C + c];
    }
    __syncthreads();
#pragma unroll
    for (int i = 0; i < 4; i++) {
        int c = c0 + ty + i * 8, r = r0 + tx;
        if (c < C && r < R) {
            size_t o = out_off + boff + (size_t)c * R + r;
            u16 v = tile[tx][ty + i * 8];
            if (isb) ((u16*)outv)[o] = v;
            else ((float*)outv)[o] = b2f(v);
        }
    }
}

// conv weight transform for all 3 levels: wt[n][tap*256+ci] = w[n][ci*9+tap]
__global__ void convw3_kernel(const void* __restrict__ w0, const void* __restrict__ w1,
                              const void* __restrict__ w2, u16* __restrict__ WtC,
                              const int* __restrict__ flag) {
    int lvl = blockIdx.y;
    const void* w = (lvl == 0) ? w0 : (lvl == 1) ? w1 : w2;
    u16* wt = WtC + (size_t)lvl * 256 * 2304;
    int i = blockIdx.x * 256 + threadIdx.x;
    if (i >= 256 * 2304) return;
    int n = i / 2304;
    int k = i - n * 2304;
    int tap = k >> 8, ci = k & 255;
    int si = n * 2304 + ci * 9 + tap;
    wt[i] = flag[0] ? ((const u16*)w)[si] : f2b(((const float*)w)[si]);
}

// ---------------- GNN gather: T = bf16(H + segsum(H[src]) * invdeg) ----------------
__global__ __launch_bounds__(256) void gather_kernel(
    const u16* __restrict__ H, const int* __restrict__ csr, const int* __restrict__ rs,
    const float* __restrict__ invdeg, u16* __restrict__ T, int ecap) {
    int node = blockIdx.x * 4 + (threadIdx.x >> 6);
    if (node >= NNi) return;
    int lane = threadIdx.x & 63;
    int c = lane * 4;
    int e0 = rs[node], e1 = rs[node + 1];
    e0 = e0 < 0 ? 0 : e0;
    e1 = e1 > ecap ? ecap : e1;
    float s0 = 0.f, s1 = 0.f, s2 = 0.f, s3 = 0.f;
    int srcn = (e0 < e1) ? csr[e0] : 0;
    for (int e = e0; e < e1; e++) {
        int src = srcn;
        if (e + 1 < e1) srcn = csr[e + 1];  // prefetch next index under this row load
        src = ((unsigned)src < (unsigned)NNi) ? src : 0;
        ushort4 hv = *(const ushort4*)(H + (size_t)src * 256 + c);
        s0 += b2f(hv.x); s1 += b2f(hv.y); s2 += b2f(hv.z); s3 += b2f(hv.w);
    }
    float inv = invdeg[node];
    ushort4 hv = *(const ushort4*)(H + (size_t)node * 256 + c);
    ushort4 o;
    o.x = f2b(b2f(hv.x) + s0 * inv);
    o.y = f2b(b2f(hv.y) + s1 * inv);
    o.z = f2b(b2f(hv.z) + s2 * inv);
    o.w = f2b(b2f(hv.w) + s3 * inv);
    *(ushort4*)(T + (size_t)node * 256 + c) = o;
}

// ---------------- MFMA GEMM body with 2-phase register prefetch ----------------
// C[M,256] = A[M,K] @ Bt[256,K]^T + bias, opt relu. Next k-step's global loads are
// issued right after the second barrier so VMEM latency overlaps ds_read+MFMA+barrier
// (previously the load sat exposed between barriers at ~1.5 blocks/CU occupancy).
template <bool CONV, bool RELU>
__device__ __forceinline__ void gemm_body(
    u16 (* __restrict__ As)[40], u16 (* __restrict__ Bs)[40],
    const u16* __restrict__ A, int lda,
    const u16* __restrict__ Bt, int ldb,
    const u16* __restrict__ bias,
    u16* __restrict__ out, u16* __restrict__ out2,
    int M, int K, int H, int W, int m0, int n0) {
    int t = threadIdx.x;
    int wave = t >> 6, lane = t & 63;
    int wm = wave & 1, wn = wave >> 1;
    f32x4 acc[4][4] = {};

    int r = t >> 1;
    int seg = (t & 1) * 16;

    int arow = m0 + r;
    bool arow_ok = arow < M;
    int y_ = 0, x_ = 0;
    if (CONV && arow_ok) {
        int HW = H * W;
        int b = arow / HW;
        int rem = arow - b * HW;
        y_ = rem / W;
        x_ = rem - y_ * W;
    }
    const u16* aptr = A + (size_t)arow * lda + seg;
    const u16* bptr = Bt + (size_t)(n0 + r) * ldb + seg;

    uint4 av0, av1, bv0, bv1;
    auto load_a = [&](int k0) {
        uint4 z = make_uint4(0, 0, 0, 0);
        av0 = z; av1 = z;
        if (!CONV) {
            if (arow_ok) {
                av0 = *(const uint4*)(aptr + k0);
                av1 = *(const uint4*)(aptr + k0 + 8);
            }
        } else {
            int tap = k0 >> 8;
            int ty = tap / 3;
            int dy = ty - 1, dx = tap - ty * 3 - 1;
            int yy = y_ + dy, xx = x_ + dx;
            if (arow_ok && (unsigned)yy < (unsigned)H && (unsigned)xx < (unsigned)W) {
                const u16* p = A + (size_t)(arow + dy * W + dx) * lda + (k0 & 255) + seg;
                av0 = *(const uint4*)p;
                av1 = *(const uint4*)(p + 8);
            }
        }
    };

    load_a(0);
    bv0 = *(const uint4*)(bptr);
    bv1 = *(const uint4*)(bptr + 8);

    for (int k0 = 0; k0 < K; k0 += 32) {
        __syncthreads();
        *(uint4*)&As[r][seg] = av0;
        *(uint4*)&As[r][seg + 8] = av1;
        *(uint4*)&Bs[r][seg] = bv0;
        *(uint4*)&Bs[r][seg + 8] = bv1;
        __syncthreads();
        int kn = k0 + 32;
        if (kn < K) {  // issue next-slab loads early: latency hides under MFMA phase
            load_a(kn);
            bv0 = *(const uint4*)(bptr + kn);
            bv1 = *(const uint4*)(bptr + kn + 8);
        }
        int fm = lane & 15;
        int kq = (lane >> 4) * 8;
        bf16x8 af[4], bfv[4];
#pragma unroll
        for (int i = 0; i < 4; i++) af[i] = *(const bf16x8*)&As[wm * 64 + i * 16 + fm][kq];
#pragma unroll
        for (int j = 0; j < 4; j++) bfv[j] = *(const bf16x8*)&Bs[wn * 64 + j * 16 + fm][kq];
#pragma unroll
        for (int i = 0; i < 4; i++)
#pragma unroll
            for (int j = 0; j < 4; j++)
                acc[i][j] = __builtin_amdgcn_mfma_f32_16x16x32_bf16(af[i], bfv[j], acc[i][j], 0, 0, 0);
    }

    int q = lane >> 4, nl = lane & 15;
#pragma unroll
    for (int j = 0; j < 4; j++) {
        int n = n0 + wn * 64 + j * 16 + nl;
        float bv = b2f(bias[n]);
#pragma unroll
        for (int i = 0; i < 4; i++) {
            int mbase = m0 + wm * 64 + i * 16 + q * 4;
#pragma unroll
            for (int rg = 0; rg < 4; rg++) {
                int m = mbase + rg;
                if (m < M) {
                    float v = acc[i][j][rg] + bv;
                    if (RELU) v = fmaxf(v, 0.f);
                    u16 bs = f2b(v);
                    out[(size_t)m * 256 + n] = bs;
                    if (out2) out2[(size_t)m * 256 + n] = bs;
                }
            }
        }
    }
}

// generic wrapper (GNN layers)
template <bool CONV, bool RELU>
__global__ __launch_bounds__(256) void gemm_kernel(
    const u16* __restrict__ A, int lda,
    const u16* __restrict__ Bt, int ldb,
    const u16* __restrict__ bias,
    u16* __restrict__ out, u16* __restrict__ out2,
    int M, int K, int H, int W) {
    __shared__ __align__(16) u16 As[128][40];
    __shared__ __align__(16) u16 Bs[128][40];
    gemm_body<CONV, RELU>(As, Bs, A, lda, Bt, ldb, bias, out, out2, M, K, H, W,
                          blockIdx.y * 128, blockIdx.x * 128);
}

// all 3 lateral 1x1 GEMMs, one launch; y-range selects level (K differs per level)
__global__ __launch_bounds__(256) void lat_all_kernel(
    const u16* __restrict__ Xt3, const u16* __restrict__ Xt4, const u16* __restrict__ Xt5,
    const u16* __restrict__ W1, const u16* __restrict__ BB,
    u16* __restrict__ P, u16* __restrict__ Ha) {
    __shared__ __align__(16) u16 As[128][40];
    __shared__ __align__(16) u16 Bs[128][40];
    int by = blockIdx.y;
    const u16* A; const u16* Bt; const u16* bias;
    int K, Ml, m0; size_t off;
    if (by < 200)      { A = Xt3; Bt = W1;          bias = BB;       K = 256; Ml = N3i; off = 0;                          m0 = by * 128; }
    else if (by < 250) { A = Xt4; Bt = W1 + 65536;  bias = BB + 256; K = 512; Ml = N4i; off = (size_t)N3i * 256;          m0 = (by - 200) * 128; }
    else               { A = Xt5; Bt = W1 + 196608; bias = BB + 512; K = 512; Ml = N5i; off = (size_t)(N3i + N4i) * 256;  m0 = (by - 250) * 128; }
    gemm_body<false, false>(As, Bs, A, K, Bt, K, bias, P + off, Ha + off, Ml, K, 0, 0,
                            m0, blockIdx.x * 128);
}

// all 3 output 3x3 convs, one launch (526 equal-cost blocks; kills the 100/26-block tails)
__global__ __launch_bounds__(256) void conv_gemm_all(
    const u16* __restrict__ Pc, const u16* __restrict__ WtC,
    const u16* __restrict__ BB, u16* __restrict__ OutT) {
    __shared__ __align__(16) u16 As[128][40];
    __shared__ __align__(16) u16 Bs[128][40];
    int by = blockIdx.y;
    int lvl, yl, Hd, Ml; size_t base;
    if (by < 200)      { lvl = 0; yl = by;       Hd = 80; Ml = N3i; base = 0; }
    else if (by < 250) { lvl = 1; yl = by - 200; Hd = 40; Ml = N4i; base = (size_t)N3i * 256; }
    else               { lvl = 2; yl = by - 250; Hd = 20; Ml = N5i; base = (size_t)(N3i + N4i) * 256; }
    gemm_body<true, false>(As, Bs, Pc + base, 256, WtC + (size_t)lvl * 256 * 2304, 2304,
                           BB + 3072 + lvl * 256, OutT + base, nullptr,
                           Ml, 2304, Hd, Hd, yl * 128, blockIdx.x * 128);
}

// ---------------- fused pyramid composition: Pc = compose(P, Hf) ----------------
// q5: P5+Hf5; q4: P4+Hf4+(P5+Hf5)[par]; q3: P3+Hf3+(P4+Hf4)[p4]+(P5+Hf5)[p5]
// (expanded algebraically so all levels are independent -> one launch, no in-place races)
__global__ void pyr_kernel(const u16* __restrict__ P, const u16* __restrict__ Hf,
                           u16* __restrict__ Pc) {
    int i = blockIdx.x * 256 + threadIdx.x;
    if (i >= NNi * 64) return;
    int node = i >> 6, c = (i & 63) * 4;
    size_t bi = (size_t)node * 256 + c;
    ushort4 pv = *(const ushort4*)(P + bi);
    ushort4 hv = *(const ushort4*)(Hf + bi);
    float v0 = b2f(pv.x) + b2f(hv.x);
    float v1 = b2f(pv.y) + b2f(hv.y);
    float v2 = b2f(pv.z) + b2f(hv.z);
    float v3 = b2f(pv.w) + b2f(hv.w);
    if (node < N3i) {
        int b = node / 6400, rem = node - b * 6400;
        int y = rem / 80, x = rem - y * 80;
        size_t s4 = ((size_t)N3i + b * 1600 + (y >> 1) * 40 + (x >> 1)) * 256 + c;
        size_t s5 = ((size_t)(N3i + N4i) + b * 400 + (y >> 2) * 20 + (x >> 2)) * 256 + c;
        ushort4 p4 = *(const ushort4*)(P + s4), h4 = *(const ushort4*)(Hf + s4);
        ushort4 p5 = *(const ushort4*)(P + s5), h5 = *(const ushort4*)(Hf + s5);
        v0 += b2f(p4.x) + b2f(h4.x) + b2f(p5.x) + b2f(h5.x);
        v1 += b2f(p4.y) + b2f(h4.y) + b2f(p5.y) + b2f(h5.y);
        v2 += b2f(p4.z) + b2f(h4.z) + b2f(p5.z) + b2f(h5.z);
        v3 += b2f(p4.w) + b2f(h4.w) + b2f(p5.w) + b2f(h5.w);
    } else if (node < N3i + N4i) {
        int n4 = node - N3i;
        int b = n4 / 1600, rem = n4 - b * 1600;
        int y = rem / 40, x = rem - y * 40;
        size_t s5 = ((size_t)(N3i + N4i) + b * 400 + (y >> 1) * 20 + (x >> 1)) * 256 + c;
        ushort4 p5 = *(const ushort4*)(P + s5), h5 = *(const ushort4*)(Hf + s5);
        v0 += b2f(p5.x) + b2f(h5.x);
        v1 += b2f(p5.y) + b2f(h5.y);
        v2 += b2f(p5.z) + b2f(h5.z);
        v3 += b2f(p5.w) + b2f(h5.w);
    }
    ushort4 o;
    o.x = f2b(v0); o.y = f2b(v1); o.z = f2b(v2); o.w = f2b(v3);
    *(ushort4*)(Pc + bi) = o;
}

// ---------------- host ----------------
extern "C" void kernel_launch(void* const* d_in, const int* in_sizes, int n_in,
                              void* d_out, int out_size, void* d_ws, size_t ws_size,
                              hipStream_t stream) {
    (void)in_sizes; (void)n_in; (void)out_size; (void)ws_size;
    const void* c3 = d_in[0];
    const void* c4 = d_in[1];
    const void* c5 = d_in[2];
    const void* w3_1 = d_in[3];
    const void* b3_1 = d_in[4];
    const void* w4_1 = d_in[5];
    const void* b4_1 = d_in[6];
    const void* w5_1 = d_in[7];
    const void* b5_1 = d_in[8];
    const void* w3_3 = d_in[9];
    const void* b3_3 = d_in[10];
    const void* w4_3 = d_in[11];
    const void* b4_3 = d_in[12];
    const void* w5_3 = d_in[13];
    const void* b5_3 = d_in[14];
    const void* Wc = d_in[15];
    const void* bc = d_in[16];
    const void* Wh = d_in[17];
    const void* bh = d_in[18];
    const int* src_c = (const int*)d_in[19];
    const int* dst_c = (const int*)d_in[20];
    const int* src_h = (const int*)d_in[21];
    const int* dst_h = (const int*)d_in[22];

    char* w = (char*)d_ws;
    auto alloc = [&](size_t bytes) -> void* {
        void* p = (void*)w;
        w += (bytes + 255) & ~(size_t)255;
        return p;
    };
    // XT region: holds Xt3/Xt4/Xt5 (21.3 MB); after laterals it hosts T/Pc (17.2 MB) + WtC (3.54 MB)
    u16* XT  = (u16*)alloc(((size_t)N3i * 256 + (size_t)N4i * 512 + (size_t)N5i * 512) * 2);
    u16* Xt3 = XT;
    u16* Xt4 = XT + (size_t)N3i * 256;
    u16* Xt5 = Xt4 + (size_t)N4i * 512;
    u16* T   = XT;                          // alias (17,203,200 B <= 21,299,200 B region)
    u16* Pc  = XT;                          // pyramid output aliases T (free after GNN)
    u16* WtC = XT + (size_t)NNi * 256;      // alias, starts right after T (3.54 MB fits)
    u16* WtG = (u16*)alloc((size_t)9 * 65536 * 2);
    u16* W1  = (u16*)alloc((size_t)(65536 + 131072 + 131072) * 2);
    u16* BB  = (u16*)alloc((size_t)3840 * 2);   // biases: 3 lat | 6 bc | 3 bh | 3 conv
    u16* P   = (u16*)alloc((size_t)NNi * 256 * 2);
    u16* Ha  = (u16*)alloc((size_t)NNi * 256 * 2);
    u16* Hb  = (u16*)d_out;                 // alias d_out as scratch (>=17.2 MB either dtype)
    int* csr_c = (int*)alloc((size_t)ECi * 4);
    int* csr_h = (int*)alloc((size_t)EHi * 4);
    int* cnt2  = (int*)alloc((size_t)2 * NNi * 4);
    int* cnt_c = cnt2;
    int* cnt_h = cnt2 + NNi;
    int* rs_c  = (int*)alloc((size_t)(NNi + 1) * 4);
    int* rs_h  = (int*)alloc((size_t)(NNi + 1) * 4);
    int* cur_c = (int*)alloc((size_t)NNi * 4);
    int* cur_h = (int*)alloc((size_t)NNi * 4);
    float* inv_c = (float*)alloc((size_t)NNi * 4);
    float* inv_h = (float*)alloc((size_t)NNi * 4);
    int* flag  = (int*)alloc(256);

    // ---- dtype detection ----
    detect_kernel<<<1, 64, 0, stream>>>(c3, flag);

    // ---- CSR build (dtype-independent) ----
    zero_i32<<<(2 * NNi + 255) / 256, 256, 0, stream>>>(cnt2, 2 * NNi);
    hist2_kernel<<<(ECi + EHi + 255) / 256, 256, 0, stream>>>(dst_c, dst_h, cnt_c, cnt_h);
    scan2_kernel<<<2, 1024, 0, stream>>>(cnt_c, rs_c, cur_c, inv_c,
                                         cnt_h, rs_h, cur_h, inv_h, NNi);
    fill2_kernel<<<(ECi + EHi + 255) / 256, 256, 0, stream>>>(
        src_c, dst_c, cur_c, csr_c, src_h, dst_h, cur_h, csr_h);

    // ---- convert small tensors (one launch) ----
    CvtJobs cj;
    cj.src[0] = w3_1; cj.dst[0] = W1;          cj.n[0] = 65536;
    cj.src[1] = w4_1; cj.dst[1] = W1 + 65536;  cj.n[1] = 131072;
    cj.src[2] = w5_1; cj.dst[2] = W1 + 196608; cj.n[2] = 131072;
    cj.src[3] = b3_1; cj.dst[3] = BB;          cj.n[3] = 256;
    cj.src[4] = b4_1; cj.dst[4] = BB + 256;    cj.n[4] = 256;
    cj.src[5] = b5_1; cj.dst[5] = BB + 512;    cj.n[5] = 256;
    cj.src[6] = bc;   cj.dst[6] = BB + 768;    cj.n[6] = 1536;
    cj.src[7] = bh;   cj.dst[7] = BB + 2304;   cj.n[7] = 768;
    cj.src[8] = b3_3; cj.dst[8] = BB + 3072;   cj.n[8] = 256;
    cj.src[9] = b4_3; cj.dst[9] = BB + 3328;   cj.n[9] = 256;
    cj.src[10] = b5_3; cj.dst[10] = BB + 3584; cj.n[10] = 256;
    cvt_all_kernel<<<dim3(512, 11), 256, 0, stream>>>(cj, flag);

    // ---- input transposes (NCHW -> node-major) + GNN weight transposes ----
    transpose_in3<<<dim3(263, 16, 4), dim3(32, 8), 0, stream>>>(c3, c4, c5, Xt3, Xt4, Xt5, flag);
    transpose_w<<<dim3(8, 8, 9), dim3(32, 8), 0, stream>>>(Wc, Wh, WtG, flag);

    // ---- lateral 1x1 convs -> P (and H0 = Ha), one launch ----
    lat_all_kernel<<<dim3(2, 263), 256, 0, stream>>>(Xt3, Xt4, Xt5, W1, BB, P, Ha);

    // ---- conv weights AFTER laterals (WtC aliases Xt4/Xt5 tail) ----
    convw3_kernel<<<dim3(2304, 3), 256, 0, stream>>>(w3_3, w4_3, w5_3, WtC, flag);

    // ---- 9 GNN layers (T aliases XT[0..17.2MB], untouched by WtC) ----
    u16* Hcur = Ha;
    u16* Hnxt = Hb;
    for (int l = 0; l < 9; l++) {
        bool ctx = (l < 3) || (l >= 6);
        const int* csr = ctx ? csr_c : csr_h;
        const int* rs = ctx ? rs_c : rs_h;
        const float* inv = ctx ? inv_c : inv_h;
        int ecap = ctx ? ECi : EHi;
        int wi = (l < 3) ? l : (l < 6 ? 6 + (l - 3) : l - 3);
        const u16* bias = (l < 3) ? BB + 768 + l * 256
                        : (l < 6 ? BB + 2304 + (l - 3) * 256 : BB + 768 + (l - 3) * 256);
        gather_kernel<<<(NNi + 3) / 4, 256, 0, stream>>>(Hcur, csr, rs, inv, T, ecap);
        gemm_kernel<false, true><<<dim3(2, 263), 256, 0, stream>>>(
            T, 256, WtG + (size_t)wi * 65536, 256, bias, Hnxt, nullptr, NNi, 256, 0, 0);
        u16* tmp = Hcur; Hcur = Hnxt; Hnxt = tmp;
    }
    // after 9 swaps: Hcur = Hb (= d_out scratch), Hnxt = Ha -> reuse Ha for conv output
    u16* OutT = Hnxt;

    // ---- fused pyramid composition -> Pc (T region; frees P-in-place ordering constraint) ----
    pyr_kernel<<<(NNi * 64 + 255) / 256, 256, 0, stream>>>(P, Hcur, Pc);

    // ---- 3x3 convs (9-tap gathered GEMM), one launch, 526 equal-cost blocks ----
    conv_gemm_all<<<dim3(2, 263), 256, 0, stream>>>(Pc, WtC, BB, OutT);

    // ---- node-major -> NCHW output (one launch) ----
    transpose_out3<<<dim3(8, 263, 4), dim3(32, 8), 0, stream>>>(OutT, d_out, flag);
}

// Round 2
// 686.692 us; speedup vs baseline: 1.5629x; 1.0716x over previous
//
#include <hip/hip_runtime.h>
#include <stdint.h>

#define N3i 25600
#define N4i 6400
#define N5i 1600
#define NNi 33600
#define ECi 260000
#define EHi 120000

typedef unsigned short u16;
typedef __bf16 bf16x8 __attribute__((ext_vector_type(8)));
typedef float f32x4 __attribute__((ext_vector_type(4)));
typedef unsigned short u16x8 __attribute__((ext_vector_type(8)));

__device__ __forceinline__ float b2f(u16 u) {
    union { float f; uint32_t i; } v; v.i = ((uint32_t)u) << 16; return v.f;
}
__device__ __forceinline__ u16 f2b(float f) {
    union { float f; uint32_t i; } v; v.f = f;
    uint32_t x = v.i;
    uint32_t r = (x + 0x7FFFu + ((x >> 16) & 1u)) >> 16;  // RNE
    return (u16)r;
}

// async global->LDS, 16B per lane. LDS dest must be wave-uniform base (+lane*16 by HW);
// global source is per-lane (rule #21: swizzle via source address, keep LDS linear).
__device__ __forceinline__ void gll16(const u16* g, u16* l) {
    __builtin_amdgcn_global_load_lds((const __attribute__((address_space(1))) void*)g,
                                     (__attribute__((address_space(3))) void*)l, 16, 0, 0);
}

// ---------------- dtype detection: flag=1 if inputs are bf16, 0 if fp32 ----------------
// also zeroes the 256B zero-pad region used by masked GEMM staging
__global__ void detect_kernel(const void* __restrict__ c3raw, int* __restrict__ flag,
                              uint32_t* __restrict__ zp) {
    const uint32_t* p = (const uint32_t*)c3raw;
    int t = threadIdx.x;
    zp[t] = 0;  // 64 * 4B = 256B zero pad
    int vote = 0;
    for (int i = t; i < 256; i += 64) {
        uint32_t w = p[i];
        uint32_t lo = w & 0xFFFFu;
        uint32_t e = (lo >> 7) & 0xFFu;
        if (lo == 0u || (e >= 100u && e <= 127u)) vote++;
    }
#pragma unroll
    for (int d = 32; d >= 1; d >>= 1) vote += __shfl_down(vote, d, 64);
    if (t == 0) flag[0] = (vote >= 192) ? 1 : 0;
}

// ---------------- utility kernels ----------------
__global__ void zero_i32(int* p, int n) {
    int i = blockIdx.x * 256 + threadIdx.x;
    if (i < n) p[i] = 0;
}

__global__ void hist2_kernel(const int* __restrict__ dst_c, const int* __restrict__ dst_h,
                             int* __restrict__ cnt_c, int* __restrict__ cnt_h) {
    int i = blockIdx.x * 256 + threadIdx.x;
    if (i < ECi) {
        int d = dst_c[i];
        if ((unsigned)d < (unsigned)NNi) atomicAdd(&cnt_c[d], 1);
    } else {
        int j = i - ECi;
        if (j < EHi) {
            int d = dst_h[j];
            if ((unsigned)d < (unsigned)NNi) atomicAdd(&cnt_h[d], 1);
        }
    }
}

// wave-shuffle scan; blockIdx.x==0 -> contextual, ==1 -> hierarchical (concurrent)
__global__ __launch_bounds__(1024) void scan2_kernel(
    const int* __restrict__ cnt_c, int* __restrict__ rs_c, int* __restrict__ cur_c,
    float* __restrict__ inv_c,
    const int* __restrict__ cnt_h, int* __restrict__ rs_h, int* __restrict__ cur_h,
    float* __restrict__ inv_h, int n) {
    const int* cnt = blockIdx.x ? cnt_h : cnt_c;
    int* rs = blockIdx.x ? rs_h : rs_c;
    int* cur = blockIdx.x ? cur_h : cur_c;
    float* inv = blockIdx.x ? inv_h : inv_c;
    __shared__ int ws[16];
    __shared__ int base;
    int t = threadIdx.x, wid = t >> 6, lane = t & 63;
    if (t == 0) { base = 0; rs[0] = 0; }
    __syncthreads();
    for (int i0 = 0; i0 < n; i0 += 1024) {
        int i = i0 + t;
        int v = (i < n) ? cnt[i] : 0;
        int x = v;
#pragma unroll
        for (int d = 1; d < 64; d <<= 1) {
            int y = __shfl_up(x, d, 64);
            if (lane >= d) x += y;
        }
        if (lane == 63) ws[wid] = x;
        __syncthreads();
        if (wid == 0) {
            int s = (lane < 16) ? ws[lane] : 0;
#pragma unroll
            for (int d = 1; d < 16; d <<= 1) {
                int y = __shfl_up(s, d, 64);
                if (lane >= d) s += y;
            }
            if (lane < 16) ws[lane] = s;
        }
        __syncthreads();
        int b = base;
        int incl = x + (wid ? ws[wid - 1] : 0);
        if (i < n) {
            rs[i + 1] = b + incl;
            cur[i] = b + incl - v;
            int dv = v < 1 ? 1 : v;
            inv[i] = 1.0f / (float)dv;
        }
        int tot = ws[15];
        __syncthreads();
        if (t == 1023) base = b + tot;
        __syncthreads();
    }
}

__global__ void fill2_kernel(const int* __restrict__ src_c, const int* __restrict__ dst_c,
                             int* __restrict__ cur_c, int* __restrict__ csr_c,
                             const int* __restrict__ src_h, const int* __restrict__ dst_h,
                             int* __restrict__ cur_h, int* __restrict__ csr_h) {
    int i = blockIdx.x * 256 + threadIdx.x;
    if (i < ECi) {
        int d = dst_c[i];
        if ((unsigned)d < (unsigned)NNi) {
            int p = atomicAdd(&cur_c[d], 1);
            if ((unsigned)p < (unsigned)ECi) csr_c[p] = src_c[i];
        }
    } else {
        int j = i - ECi;
        if (j < EHi) {
            int d = dst_h[j];
            if ((unsigned)d < (unsigned)NNi) {
                int p = atomicAdd(&cur_h[d], 1);
                if ((unsigned)p < (unsigned)EHi) csr_h[p] = src_h[j];
            }
        }
    }
}

// all 11 small conversions in one launch (grid.y = job id)
struct CvtJobs { const void* src[11]; u16* dst[11]; int n[11]; };

__global__ void cvt_all_kernel(CvtJobs j, const int* __restrict__ flag) {
    int job = blockIdx.y;
    int i = blockIdx.x * 256 + threadIdx.x;
    if (i >= j.n[job]) return;
    const void* s = j.src[job];
    j.dst[job][i] = flag[0] ? ((const u16*)s)[i] : f2b(((const float*)s)[i]);
}

// ---------------- transposes ----------------
__device__ __forceinline__ void tin_body(const void* in, size_t ioff, u16* outp, int R, int C,
                                         int isb, int c0, int r0, u16 (*tile)[33]) {
    const u16* inb = (const u16*)in + ioff;
    const float* inf_ = (const float*)in + ioff;
    int tx = threadIdx.x, ty = threadIdx.y;  // block (32,8)
#pragma unroll
    for (int i = 0; i < 4; i++) {
        int r = r0 + ty + i * 8, c = c0 + tx;
        if (r < R && c < C) {
            size_t idx = (size_t)r * C + c;
            tile[ty + i * 8][tx] = isb ? inb[idx] : f2b(inf_[idx]);
        }
    }
    __syncthreads();
#pragma unroll
    for (int i = 0; i < 4; i++) {
        int c = c0 + ty + i * 8, r = r0 + tx;
        if (c < C && r < R) outp[(size_t)c * R + r] = tile[tx][ty + i * 8];
    }
}

__global__ void transpose_in3(const void* __restrict__ c3, const void* __restrict__ c4,
                              const void* __restrict__ c5, u16* __restrict__ Xt3,
                              u16* __restrict__ Xt4, u16* __restrict__ Xt5,
                              const int* __restrict__ flag) {
    __shared__ u16 tile[32][33];
    int bx = blockIdx.x;
    const void* in; u16* outb; int R, C, xb;
    if (bx < 200)      { in = c3; outb = Xt3; R = 256; C = 6400; xb = bx; }
    else if (bx < 250) { in = c4; outb = Xt4; R = 512; C = 1600; xb = bx - 200; }
    else               { in = c5; outb = Xt5; R = 512; C = 400;  xb = bx - 250; }
    int r0 = blockIdx.y * 32;
    if (r0 >= R) return;
    size_t boff = (size_t)blockIdx.z * R * C;
    tin_body(in, boff, outb + boff, R, C, flag[0], xb * 32, r0, tile);
}

__global__ void transpose_w(const void* __restrict__ Wc, const void* __restrict__ Wh,
                            u16* __restrict__ WtG, const int* __restrict__ flag) {
    __shared__ u16 tile[32][33];
    int z = blockIdx.z;
    const void* in = (z < 6) ? Wc : Wh;
    int zi = (z < 6) ? z : z - 6;
    tin_body(in, (size_t)zi * 65536, WtG + (size_t)z * 65536, 256, 256, flag[0],
             blockIdx.x * 32, blockIdx.y * 32, tile);
}

__global__ void transpose_out3(const u16* __restrict__ OutT, void* __restrict__ outv,
                               const int* __restrict__ flag) {
    __shared__ u16 tile[32][33];
    int by = blockIdx.y;
    const u16* inb; size_t out_off; int R, yb;
    if (by < 200)      { inb = OutT; out_off = 0; R = 6400; yb = by; }
    else if (by < 250) { inb = OutT + (size_t)N3i * 256; out_off = (size_t)4 * 256 * 6400; R = 1600; yb = by - 200; }
    else               { inb = OutT + (size_t)(N3i + N4i) * 256; out_off = (size_t)4 * 256 * 8000; R = 400; yb = by - 250; }
    int r0 = yb * 32;
    if (r0 >= R) return;
    const int C = 256;
    int isb = flag[0];
    int c0 = blockIdx.x * 32;
    size_t boff = (size_t)blockIdx.z * R * C;
    const u16* inp = inb + boff;
    int tx = threadIdx.x, ty = threadIdx.y;
#pragma unroll
    for (int i = 0; i < 4; i++) {
        int r = r0 + ty + i * 8, c = c0 + tx;
        if (r < R && c < C) tile[ty + i * 8][tx] = inp[(size_t)r * C + c];
    }
    __syncthreads();
#pragma unroll
    for (int i = 0; i < 4; i++) {
        int c = c0 + ty + i * 8, r = r0 + tx;
        if (c < C && r < R) {
            size_t o = out_off + boff + (size_t)c * R + r;
            u16 v = tile[tx][ty + i * 8];
            if (isb) ((u16*)outv)[o] = v;
            else ((float*)outv)[o] = b2f(v);
        }
    }
}

// conv weight transform for all 3 levels: wt[n][tap*256+ci] = w[n][ci*9+tap]
__global__ void convw3_kernel(const void* __restrict__ w0, const void* __restrict__ w1,
                              const void* __restrict__ w2, u16* __restrict__ WtC,
                              const int* __restrict__ flag) {
    int lvl = blockIdx.y;
    const void* w = (lvl == 0) ? w0 : (lvl == 1) ? w1 : w2;
    u16* wt = WtC + (size_t)lvl * 256 * 2304;
    int i = blockIdx.x * 256 + threadIdx.x;
    if (i >= 256 * 2304) return;
    int n = i / 2304;
    int k = i - n * 2304;
    int tap = k >> 8, ci = k & 255;
    int si = n * 2304 + ci * 9 + tap;
    wt[i] = flag[0] ? ((const u16*)w)[si] : f2b(((const float*)w)[si]);
}

// ---------------- GNN gather: T = bf16(H + segsum(H[src]) * invdeg) ----------------
// half-wave per edge (32 lanes x 16B = one 512B row), 2 edges in flight per wave,
// csr index prefetch; halves combined with one shfl_xor pass at the end.
__global__ __launch_bounds__(256) void gather_kernel(
    const u16* __restrict__ H, const int* __restrict__ csr, const int* __restrict__ rs,
    const float* __restrict__ invdeg, u16* __restrict__ T, int ecap) {
    int node = blockIdx.x * 4 + (threadIdx.x >> 6);
    if (node >= NNi) return;
    int lane = threadIdx.x & 63;
    int half = lane >> 5;
    int c = (lane & 31) * 8;
    int e0 = rs[node], e1 = rs[node + 1];
    e0 = e0 < 0 ? 0 : e0;
    e1 = e1 > ecap ? ecap : e1;
    const u16* Hn = H + (size_t)node * 256 + c;
    u16x8 self = *(const u16x8*)Hn;  // issue early, consumed after loop
    float s0 = 0.f, s1 = 0.f, s2 = 0.f, s3 = 0.f, s4 = 0.f, s5 = 0.f, s6 = 0.f, s7 = 0.f;
    int e = e0 + half;
    int srcn = (e < e1) ? csr[e] : 0;
    for (; e < e1; e += 2) {
        int src = srcn;
        if (e + 2 < e1) srcn = csr[e + 2];
        src = ((unsigned)src < (unsigned)NNi) ? src : 0;
        u16x8 hv = *(const u16x8*)(H + (size_t)src * 256 + c);
        s0 += b2f(hv[0]); s1 += b2f(hv[1]); s2 += b2f(hv[2]); s3 += b2f(hv[3]);
        s4 += b2f(hv[4]); s5 += b2f(hv[5]); s6 += b2f(hv[6]); s7 += b2f(hv[7]);
    }
    // combine the two half-wave partial sums (lane <-> lane^32, same channels)
    s0 += __shfl_xor(s0, 32, 64); s1 += __shfl_xor(s1, 32, 64);
    s2 += __shfl_xor(s2, 32, 64); s3 += __shfl_xor(s3, 32, 64);
    s4 += __shfl_xor(s4, 32, 64); s5 += __shfl_xor(s5, 32, 64);
    s6 += __shfl_xor(s6, 32, 64); s7 += __shfl_xor(s7, 32, 64);
    if (half == 0) {
        float inv = invdeg[node];
        u16x8 o;
        o[0] = f2b(b2f(self[0]) + s0 * inv); o[1] = f2b(b2f(self[1]) + s1 * inv);
        o[2] = f2b(b2f(self[2]) + s2 * inv); o[3] = f2b(b2f(self[3]) + s3 * inv);
        o[4] = f2b(b2f(self[4]) + s4 * inv); o[5] = f2b(b2f(self[5]) + s5 * inv);
        o[6] = f2b(b2f(self[6]) + s6 * inv); o[7] = f2b(b2f(self[7]) + s7 * inv);
        *(u16x8*)(T + (size_t)node * 256 + c) = o;
    }
}

// ---------------- MFMA GEMM body: global_load_lds + LDS double-buffer, 1 barrier/K-step ----
// LDS per buffer: A[128][32] + B[128][32] u16, linear (gll requirement). Chunk XOR-swizzle
// (chunk ^= (row>>1)&3) applied on BOTH the per-lane global source address and the
// ds_read_b128 address (rule #21) -> <=2-way bank aliasing on reads (free per m136).
// Masked rows/taps redirect the source pointer to a 256B zero page.
template <bool CONV, bool RELU>
__device__ __forceinline__ void gemm_body(
    u16 (* __restrict__ lds)[4096],
    const u16* __restrict__ A, int lda,
    const u16* __restrict__ Bt, int ldb,
    const u16* __restrict__ bias,
    const u16* __restrict__ zp,
    u16* __restrict__ out, u16* __restrict__ out2,
    int M, int K, int H, int W, int m0, int n0) {
    int t = threadIdx.x;
    int w = t >> 6, lane = t & 63;
    int wm = w & 1, wn = w >> 1;
    f32x4 acc[4][4] = {};

    // staging geometry: 512 16B-chunks per 8KB tile; this thread covers chunks g0, g1
    int g0 = w * 128 + lane;
    int g1 = g0 + 64;
    int row0 = g0 >> 2, c0 = g0 & 3;
    int row1 = g1 >> 2, c1 = g1 & 3;
    int ss0 = ((c0 ^ ((row0 >> 1) & 3)) << 3);  // source k-seg (elements) for chunk c0
    int ss1 = ((c1 ^ ((row1 >> 1) & 3)) << 3);

    int ar0 = m0 + row0, ar1 = m0 + row1;
    bool aok0 = ar0 < M, aok1 = ar1 < M;
    int y0_ = 0, x0_ = 0, y1_ = 0, x1_ = 0;
    if (CONV) {
        int HW = H * W;
        if (aok0) { int b = ar0 / HW; int rem = ar0 - b * HW; y0_ = rem / W; x0_ = rem - y0_ * W; }
        if (aok1) { int b = ar1 / HW; int rem = ar1 - b * HW; y1_ = rem / W; x1_ = rem - y1_ * W; }
    }
    const u16* aP0 = A + (size_t)ar0 * lda + ss0;
    const u16* aP1 = A + (size_t)ar1 * lda + ss1;
    const u16* bP0 = Bt + (size_t)(n0 + row0) * ldb + ss0;
    const u16* bP1 = Bt + (size_t)(n0 + row1) * ldb + ss1;

    int lbase = w * 1024;  // u16 units; wave-uniform LDS slice base

    auto stage = [&](int bf, int k0) {
        u16* LA = lds[bf * 2];
        u16* LB = lds[bf * 2 + 1];
        const u16* sa0;
        const u16* sa1;
        if (!CONV) {
            sa0 = aok0 ? aP0 + k0 : zp;
            sa1 = aok1 ? aP1 + k0 : zp;
        } else {
            int tap = k0 >> 8;
            int t3 = tap / 3;
            int dy = t3 - 1, dx = tap - t3 * 3 - 1;
            int off = (dy * W + dx) * lda + (k0 & 255);
            int yy0 = y0_ + dy, xx0 = x0_ + dx;
            int yy1 = y1_ + dy, xx1 = x1_ + dx;
            sa0 = (aok0 && (unsigned)yy0 < (unsigned)H && (unsigned)xx0 < (unsigned)W) ? aP0 + off : zp;
            sa1 = (aok1 && (unsigned)yy1 < (unsigned)H && (unsigned)xx1 < (unsigned)W) ? aP1 + off : zp;
        }
        gll16(sa0, LA + lbase);
        gll16(sa1, LA + lbase + 512);
        gll16(bP0 + k0, LB + lbase);
        gll16(bP1 + k0, LB + lbase + 512);
    };

    int nst = K >> 5;
    int fm = lane & 15;
    int co = (((lane >> 4) ^ ((fm >> 1) & 3)) << 3);  // swizzled k-chunk offset (u16)

    stage(0, 0);
    __syncthreads();  // implicit vmcnt(0) drain -> buf0 ready
    for (int s = 0; s < nst; s++) {
        int bf = s & 1;
        if (s + 1 < nst) stage(bf ^ 1, (s + 1) << 5);  // in flight during compute
        const u16* LA = lds[bf * 2];
        const u16* LB = lds[bf * 2 + 1];
        bf16x8 af[4], bfv[4];
#pragma unroll
        for (int i = 0; i < 4; i++) af[i] = *(const bf16x8*)&LA[(wm * 64 + i * 16 + fm) * 32 + co];
#pragma unroll
        for (int j = 0; j < 4; j++) bfv[j] = *(const bf16x8*)&LB[(wn * 64 + j * 16 + fm) * 32 + co];
#pragma unroll
        for (int i = 0; i < 4; i++)
#pragma unroll
            for (int j = 0; j < 4; j++)
                acc[i][j] = __builtin_amdgcn_mfma_f32_16x16x32_bf16(af[i], bfv[j], acc[i][j], 0, 0, 0);
        __syncthreads();  // drains stage loads (next buf ready) + guards buf reuse
    }

    int q = lane >> 4, nl = lane & 15;
#pragma unroll
    for (int j = 0; j < 4; j++) {
        int n = n0 + wn * 64 + j * 16 + nl;
        float bv = b2f(bias[n]);
#pragma unroll
        for (int i = 0; i < 4; i++) {
            int mbase = m0 + wm * 64 + i * 16 + q * 4;
#pragma unroll
            for (int rg = 0; rg < 4; rg++) {
                int m = mbase + rg;
                if (m < M) {
                    float v = acc[i][j][rg] + bv;
                    if (RELU) v = fmaxf(v, 0.f);
                    u16 bs = f2b(v);
                    out[(size_t)m * 256 + n] = bs;
                    if (out2) out2[(size_t)m * 256 + n] = bs;
                }
            }
        }
    }
}

// generic wrapper (GNN layers)
template <bool CONV, bool RELU>
__global__ __launch_bounds__(256) void gemm_kernel(
    const u16* __restrict__ A, int lda,
    const u16* __restrict__ Bt, int ldb,
    const u16* __restrict__ bias,
    const u16* __restrict__ zp,
    u16* __restrict__ out, u16* __restrict__ out2,
    int M, int K, int H, int W) {
    __shared__ __align__(16) u16 lds[4][4096];
    gemm_body<CONV, RELU>(lds, A, lda, Bt, ldb, bias, zp, out, out2, M, K, H, W,
                          blockIdx.y * 128, blockIdx.x * 128);
}

// all 3 lateral 1x1 GEMMs, one launch; y-range selects level (K differs per level)
__global__ __launch_bounds__(256) void lat_all_kernel(
    const u16* __restrict__ Xt3, const u16* __restrict__ Xt4, const u16* __restrict__ Xt5,
    const u16* __restrict__ W1, const u16* __restrict__ BB, const u16* __restrict__ zp,
    u16* __restrict__ P, u16* __restrict__ Ha) {
    __shared__ __align__(16) u16 lds[4][4096];
    int by = blockIdx.y;
    const u16* A; const u16* Bt; const u16* bias;
    int K, Ml, m0; size_t off;
    if (by < 200)      { A = Xt3; Bt = W1;          bias = BB;       K = 256; Ml = N3i; off = 0;                          m0 = by * 128; }
    else if (by < 250) { A = Xt4; Bt = W1 + 65536;  bias = BB + 256; K = 512; Ml = N4i; off = (size_t)N3i * 256;          m0 = (by - 200) * 128; }
    else               { A = Xt5; Bt = W1 + 196608; bias = BB + 512; K = 512; Ml = N5i; off = (size_t)(N3i + N4i) * 256;  m0 = (by - 250) * 128; }
    gemm_body<false, false>(lds, A, K, Bt, K, bias, zp, P + off, Ha + off, Ml, K, 0, 0,
                            m0, blockIdx.x * 128);
}

// all 3 output 3x3 convs, one launch (526 equal-cost blocks)
__global__ __launch_bounds__(256) void conv_gemm_all(
    const u16* __restrict__ Pc, const u16* __restrict__ WtC,
    const u16* __restrict__ BB, const u16* __restrict__ zp, u16* __restrict__ OutT) {
    __shared__ __align__(16) u16 lds[4][4096];
    int by = blockIdx.y;
    int lvl, yl, Hd, Ml; size_t base;
    if (by < 200)      { lvl = 0; yl = by;       Hd = 80; Ml = N3i; base = 0; }
    else if (by < 250) { lvl = 1; yl = by - 200; Hd = 40; Ml = N4i; base = (size_t)N3i * 256; }
    else               { lvl = 2; yl = by - 250; Hd = 20; Ml = N5i; base = (size_t)(N3i + N4i) * 256; }
    gemm_body<true, false>(lds, Pc + base, 256, WtC + (size_t)lvl * 256 * 2304, 2304,
                           BB + 3072 + lvl * 256, zp, OutT + base, nullptr,
                           Ml, 2304, Hd, Hd, yl * 128, blockIdx.x * 128);
}

// ---------------- fused pyramid composition: Pc = compose(P, Hf) ----------------
__global__ void pyr_kernel(const u16* __restrict__ P, const u16* __restrict__ Hf,
                           u16* __restrict__ Pc) {
    int i = blockIdx.x * 256 + threadIdx.x;
    if (i >= NNi * 64) return;
    int node = i >> 6, c = (i & 63) * 4;
    size_t bi = (size_t)node * 256 + c;
    ushort4 pv = *(const ushort4*)(P + bi);
    ushort4 hv = *(const ushort4*)(Hf + bi);
    float v0 = b2f(pv.x) + b2f(hv.x);
    float v1 = b2f(pv.y) + b2f(hv.y);
    float v2 = b2f(pv.z) + b2f(hv.z);
    float v3 = b2f(pv.w) + b2f(hv.w);
    if (node < N3i) {
        int b = node / 6400, rem = node - b * 6400;
        int y = rem / 80, x = rem - y * 80;
        size_t s4 = ((size_t)N3i + b * 1600 + (y >> 1) * 40 + (x >> 1)) * 256 + c;
        size_t s5 = ((size_t)(N3i + N4i) + b * 400 + (y >> 2) * 20 + (x >> 2)) * 256 + c;
        ushort4 p4 = *(const ushort4*)(P + s4), h4 = *(const ushort4*)(Hf + s4);
        ushort4 p5 = *(const ushort4*)(P + s5), h5 = *(const ushort4*)(Hf + s5);
        v0 += b2f(p4.x) + b2f(h4.x) + b2f(p5.x) + b2f(h5.x);
        v1 += b2f(p4.y) + b2f(h4.y) + b2f(p5.y) + b2f(h5.y);
        v2 += b2f(p4.z) + b2f(h4.z) + b2f(p5.z) + b2f(h5.z);
        v3 += b2f(p4.w) + b2f(h4.w) + b2f(p5.w) + b2f(h5.w);
    } else if (node < N3i + N4i) {
        int n4 = node - N3i;
        int b = n4 / 1600, rem = n4 - b * 1600;
        int y = rem / 40, x = rem - y * 40;
        size_t s5 = ((size_t)(N3i + N4i) + b * 400 + (y >> 1) * 20 + (x >> 1)) * 256 + c;
        ushort4 p5 = *(const ushort4*)(P + s5), h5 = *(const ushort4*)(Hf + s5);
        v0 += b2f(p5.x) + b2f(h5.x);
        v1 += b2f(p5.y) + b2f(h5.y);
        v2 += b2f(p5.z) + b2f(h5.z);
        v3 += b2f(p5.w) + b2f(h5.w);
    }
    ushort4 o;
    o.x = f2b(v0); o.y = f2b(v1); o.z = f2b(v2); o.w = f2b(v3);
    *(ushort4*)(Pc + bi) = o;
}

// ---------------- host ----------------
extern "C" void kernel_launch(void* const* d_in, const int* in_sizes, int n_in,
                              void* d_out, int out_size, void* d_ws, size_t ws_size,
                              hipStream_t stream) {
    (void)in_sizes; (void)n_in; (void)out_size; (void)ws_size;
    const void* c3 = d_in[0];
    const void* c4 = d_in[1];
    const void* c5 = d_in[2];
    const void* w3_1 = d_in[3];
    const void* b3_1 = d_in[4];
    const void* w4_1 = d_in[5];
    const void* b4_1 = d_in[6];
    const void* w5_1 = d_in[7];
    const void* b5_1 = d_in[8];
    const void* w3_3 = d_in[9];
    const void* b3_3 = d_in[10];
    const void* w4_3 = d_in[11];
    const void* b4_3 = d_in[12];
    const void* w5_3 = d_in[13];
    const void* b5_3 = d_in[14];
    const void* Wc = d_in[15];
    const void* bc = d_in[16];
    const void* Wh = d_in[17];
    const void* bh = d_in[18];
    const int* src_c = (const int*)d_in[19];
    const int* dst_c = (const int*)d_in[20];
    const int* src_h = (const int*)d_in[21];
    const int* dst_h = (const int*)d_in[22];

    char* w = (char*)d_ws;
    auto alloc = [&](size_t bytes) -> void* {
        void* p = (void*)w;
        w += (bytes + 255) & ~(size_t)255;
        return p;
    };
    u16* XT  = (u16*)alloc(((size_t)N3i * 256 + (size_t)N4i * 512 + (size_t)N5i * 512) * 2);
    u16* Xt3 = XT;
    u16* Xt4 = XT + (size_t)N3i * 256;
    u16* Xt5 = Xt4 + (size_t)N4i * 512;
    u16* T   = XT;                          // alias (17.2 MB <= 21.3 MB region)
    u16* Pc  = XT;                          // pyramid output aliases T (free after GNN)
    u16* WtC = XT + (size_t)NNi * 256;      // alias, starts right after T (3.54 MB fits)
    u16* WtG = (u16*)alloc((size_t)9 * 65536 * 2);
    u16* W1  = (u16*)alloc((size_t)(65536 + 131072 + 131072) * 2);
    u16* BB  = (u16*)alloc((size_t)3840 * 2);
    u16* P   = (u16*)alloc((size_t)NNi * 256 * 2);
    u16* Ha  = (u16*)alloc((size_t)NNi * 256 * 2);
    u16* Hb  = (u16*)d_out;                 // alias d_out as scratch
    int* csr_c = (int*)alloc((size_t)ECi * 4);
    int* csr_h = (int*)alloc((size_t)EHi * 4);
    int* cnt2  = (int*)alloc((size_t)2 * NNi * 4);
    int* cnt_c = cnt2;
    int* cnt_h = cnt2 + NNi;
    int* rs_c  = (int*)alloc((size_t)(NNi + 1) * 4);
    int* rs_h  = (int*)alloc((size_t)(NNi + 1) * 4);
    int* cur_c = (int*)alloc((size_t)NNi * 4);
    int* cur_h = (int*)alloc((size_t)NNi * 4);
    float* inv_c = (float*)alloc((size_t)NNi * 4);
    float* inv_h = (float*)alloc((size_t)NNi * 4);
    int* flag  = (int*)alloc(256);
    u16* zp    = (u16*)alloc(256);          // zero page for masked GEMM staging

    // ---- dtype detection + zero-pad init ----
    detect_kernel<<<1, 64, 0, stream>>>(c3, flag, (uint32_t*)zp);

    // ---- CSR build ----
    zero_i32<<<(2 * NNi + 255) / 256, 256, 0, stream>>>(cnt2, 2 * NNi);
    hist2_kernel<<<(ECi + EHi + 255) / 256, 256, 0, stream>>>(dst_c, dst_h, cnt_c, cnt_h);
    scan2_kernel<<<2, 1024, 0, stream>>>(cnt_c, rs_c, cur_c, inv_c,
                                         cnt_h, rs_h, cur_h, inv_h, NNi);
    fill2_kernel<<<(ECi + EHi + 255) / 256, 256, 0, stream>>>(
        src_c, dst_c, cur_c, csr_c, src_h, dst_h, cur_h, csr_h);

    // ---- convert small tensors (one launch) ----
    CvtJobs cj;
    cj.src[0] = w3_1; cj.dst[0] = W1;          cj.n[0] = 65536;
    cj.src[1] = w4_1; cj.dst[1] = W1 + 65536;  cj.n[1] = 131072;
    cj.src[2] = w5_1; cj.dst[2] = W1 + 196608; cj.n[2] = 131072;
    cj.src[3] = b3_1; cj.dst[3] = BB;          cj.n[3] = 256;
    cj.src[4] = b4_1; cj.dst[4] = BB + 256;    cj.n[4] = 256;
    cj.src[5] = b5_1; cj.dst[5] = BB + 512;    cj.n[5] = 256;
    cj.src[6] = bc;   cj.dst[6] = BB + 768;    cj.n[6] = 1536;
    cj.src[7] = bh;   cj.dst[7] = BB + 2304;   cj.n[7] = 768;
    cj.src[8] = b3_3; cj.dst[8] = BB + 3072;   cj.n[8] = 256;
    cj.src[9] = b4_3; cj.dst[9] = BB + 3328;   cj.n[9] = 256;
    cj.src[10] = b5_3; cj.dst[10] = BB + 3584; cj.n[10] = 256;
    cvt_all_kernel<<<dim3(512, 11), 256, 0, stream>>>(cj, flag);

    // ---- input transposes + GNN weight transposes ----
    transpose_in3<<<dim3(263, 16, 4), dim3(32, 8), 0, stream>>>(c3, c4, c5, Xt3, Xt4, Xt5, flag);
    transpose_w<<<dim3(8, 8, 9), dim3(32, 8), 0, stream>>>(Wc, Wh, WtG, flag);

    // ---- lateral 1x1 convs -> P (and H0 = Ha), one launch ----
    lat_all_kernel<<<dim3(2, 263), 256, 0, stream>>>(Xt3, Xt4, Xt5, W1, BB, zp, P, Ha);

    // ---- conv weights AFTER laterals (WtC aliases Xt4/Xt5 tail) ----
    convw3_kernel<<<dim3(2304, 3), 256, 0, stream>>>(w3_3, w4_3, w5_3, WtC, flag);

    // ---- 9 GNN layers ----
    u16* Hcur = Ha;
    u16* Hnxt = Hb;
    for (int l = 0; l < 9; l++) {
        bool ctx = (l < 3) || (l >= 6);
        const int* csr = ctx ? csr_c : csr_h;
        const int* rs = ctx ? rs_c : rs_h;
        const float* inv = ctx ? inv_c : inv_h;
        int ecap = ctx ? ECi : EHi;
        int wi = (l < 3) ? l : (l < 6 ? 6 + (l - 3) : l - 3);
        const u16* bias = (l < 3) ? BB + 768 + l * 256
                        : (l < 6 ? BB + 2304 + (l - 3) * 256 : BB + 768 + (l - 3) * 256);
        gather_kernel<<<(NNi + 3) / 4, 256, 0, stream>>>(Hcur, csr, rs, inv, T, ecap);
        gemm_kernel<false, true><<<dim3(2, 263), 256, 0, stream>>>(
            T, 256, WtG + (size_t)wi * 65536, 256, bias, zp, Hnxt, nullptr, NNi, 256, 0, 0);
        u16* tmp = Hcur; Hcur = Hnxt; Hnxt = tmp;
    }
    u16* OutT = Hnxt;  // = Ha

    // ---- fused pyramid composition -> Pc ----
    pyr_kernel<<<(NNi * 64 + 255) / 256, 256, 0, stream>>>(P, Hcur, Pc);

    // ---- 3x3 convs (9-tap gathered GEMM), one launch ----
    conv_gemm_all<<<dim3(2, 263), 256, 0, stream>>>(Pc, WtC, BB, zp, OutT);

    // ---- node-major -> NCHW output (one launch) ----
    transpose_out3<<<dim3(8, 263, 4), dim3(32, 8), 0, stream>>>(OutT, d_out, flag);
}